// Round 6
// baseline (581.223 us; speedup 1.0000x reference)
//
#include <hip/hip_runtime.h>
#include <hip/hip_bf16.h>
#include <cstdint>

// MinGRU: g=sigmoid(xWg^T+bg), c=tanh(xWh^T+bh), h_t = g*h_{t-1} + (1-g)*c
// B=8, L=4096, D=1024.  M = B*L = 32768, K = E = 1024.
//
// R9 (from R8 post-mortem: B-direct was right, but issue ORDER was wrong --
// B loads issued after STAGE_A meant the pre-MFMA wait on B drained the A
// prefetch too (vmcnt retires in order) -> pipeline serialized):
//  - B fragments double-buffered in NAMED register sets, prefetched one K-step
//    ahead, issued FIRST in each phase (before STAGE_A). The only vmcnt(0) is
//    the barrier's, and by then both prefetches have had ~1242 MFMA-cycles.
//  - two-phase unrolled K-loop (even/odd), compile-time buffer indices only.
//  - A stays in LDS: double-buffered, 1 global_load_lds/thread/step, one
//    barrier per K-step, 16B-chunk XOR swizzle (0 conflicts, verified R7/R8).
//  - LDS/CU/slot ~80KB (~625cy) < MFMA 1242cy -> MFMA-bound at last.
//    Floors: MFMA 69us | HBM 33us | L2-B 25us | LDS 27us.
//  - epilogue: 4x 32-row slabs, fused per-chunk scan composite (unchanged).
// ws layout: Wg16 2M | Wh16 2M | (2M spare x2) | g fp16 64MiB | c fp16 64MiB
//            | Ac 4M | Bc 4M | Hst 4M   (x16 lives in d_out)

using u16   = unsigned short;
using f32x4 = __attribute__((ext_vector_type(4))) float;
using h16x4 = __attribute__((ext_vector_type(4))) _Float16;
using h16x8 = __attribute__((ext_vector_type(8))) _Float16;

#define M_TOTAL 32768
#define K_DIM   1024
#define E_DIM   1024
#define LCH     32     // scan chunk length
#define NCH     128    // chunks per sequence (4096/32)

// ---------------- prepass: x, Wg, Wh -> fp16 (RTNE), grid-stride ----------------
__global__ void prep(const float* __restrict__ x,
                     const float* __restrict__ wg, const float* __restrict__ wh,
                     u16* __restrict__ x16, u16* __restrict__ wg16,
                     u16* __restrict__ wh16) {
    const size_t XQ = (size_t)M_TOTAL * K_DIM / 4;   // 8388608 quads
    const size_t WQ = (size_t)K_DIM * E_DIM / 4;     // 262144 quads
    const size_t TOT = XQ + 2 * WQ;
    for (size_t i = (size_t)blockIdx.x * 256 + threadIdx.x; i < TOT;
         i += (size_t)2048 * 256) {
        const float* src;
        u16* dst;
        size_t j;
        if (i < XQ)           { src = x;  dst = x16;  j = i; }
        else if (i < XQ + WQ) { src = wg; dst = wg16; j = i - XQ; }
        else                  { src = wh; dst = wh16; j = i - XQ - WQ; }
        f32x4 f = ((const f32x4*)src)[j];
        h16x4 h;
#pragma unroll
        for (int c = 0; c < 4; ++c) h[c] = (_Float16)f[c];
        ((h16x4*)dst)[j] = h;
    }
}

__device__ inline float fast_sigmoid(float z) {
    return 1.f / (1.f + __expf(-z));
}
__device__ inline float fast_tanh(float z) {
    return 1.f - 2.f / (__expf(2.f * z) + 1.f);  // saturates correctly
}

// ---------------- GEMM + activation + per-chunk composite ----------------
// 1D grid of 2048 blocks, XCD-swizzled; 512 threads.
__global__ __launch_bounds__(512, 4) void gemm_act(
    const u16* __restrict__ x16,
    const u16* __restrict__ wg_h, const u16* __restrict__ wh_h,
    const float* __restrict__ bg, const float* __restrict__ bh,
    _Float16* __restrict__ g_out, _Float16* __restrict__ c_out,
    float* __restrict__ Ac, float* __restrict__ Bc) {

    // XCD decode: each XCD owns 32 consecutive m-tiles, e fastest -> the 8
    // blocks sharing an x m-tile are temporally adjacent on one XCD (L2 reuse),
    // and W (4MB fp16 total) stays L2-resident per XCD for direct B loads.
    const int bid   = blockIdx.x;
    const int xcd   = bid & 7;
    const int local = bid >> 3;              // 0..255
    const int mt    = xcd * 32 + (local >> 3);
    const int et    = local & 7;
    const int e0    = et * 128;
    const int m0    = mt * 128;

    // LDS: A double-buffer only (2 x 8KB), union'd with the epilogue slabs.
    // A layout: 64 lines x 128B (line = row-pair), chunk slot c holds global
    // chunk c^(line&7) -> conflict-free swizzled ds_reads, linear DMA dest.
    __shared__ __align__(16) union SM {
        struct {
            u16 A[2][512 * 8];    // 2 x 8KB
        } s;
        struct {
            float g[32][132];
            float c[32][132];
        } ep;
    } sm;

    const int tid  = threadIdx.x;
    const int lane = tid & 63;
    const int wave = tid >> 6;                // 0..7
    const int wr = wave >> 2, wc = wave & 3;  // 2x4 wave grid, wave tile 64x32
    const int lr = lane & 15;                 // row/col within 16
    const int kg = lane >> 4;                 // k-group (quad)

    // ---- per-thread A staging source decode (kt-invariant part) ----
    const int sp    = tid >> 3;
    const int sc    = tid & 7;
    const int sclog = sc ^ (sp & 7);
    const int srow  = sp * 2 + (sclog >> 2);
    const int skc   = sclog & 3;
    const u16* aSrc = x16 + (size_t)(m0 + srow) * K_DIM + skc * 8;

    // ---- A fragment LDS element-offsets (kt-invariant, hoisted) ----
    int aoff[4];
#pragma unroll
    for (int tr = 0; tr < 4; ++tr) {
        int r = wr * 64 + tr * 16 + lr;
        int p = r >> 1;
        int c = (((r & 1) << 2) | kg) ^ (p & 7);
        aoff[tr] = p * 64 + c * 8;
    }

    // ---- B global base pointers (kt-invariant): direct L2 loads ----
    const u16* bgP0 = wg_h + (size_t)(e0 + wc * 32 + 0 * 16 + lr) * K_DIM + kg * 8;
    const u16* bgP1 = wg_h + (size_t)(e0 + wc * 32 + 1 * 16 + lr) * K_DIM + kg * 8;
    const u16* bhP0 = wh_h + (size_t)(e0 + wc * 32 + 0 * 16 + lr) * K_DIM + kg * 8;
    const u16* bhP1 = wh_h + (size_t)(e0 + wc * 32 + 1 * 16 + lr) * K_DIM + kg * 8;

    f32x4 accg[4][2], acch[4][2];
#pragma unroll
    for (int tr = 0; tr < 4; ++tr)
#pragma unroll
        for (int tc = 0; tc < 2; ++tc) {
            accg[tr][tc] = (f32x4){0.f, 0.f, 0.f, 0.f};
            acch[tr][tc] = (f32x4){0.f, 0.f, 0.f, 0.f};
        }

#define STAGE_A(bi, kt)                                                        \
    __builtin_amdgcn_global_load_lds(                                          \
        (const __attribute__((address_space(1))) void*)(aSrc + (size_t)(kt) * 32),\
        (__attribute__((address_space(3))) void*)(&sm.s.A[bi][tid * 8]), 16, 0, 0)

    // B register double-buffer: named even/odd sets (no runtime indexing).
    h16x8 bgE0, bgE1, bhE0, bhE1;   // even-kt set
    h16x8 bgO0, bgO1, bhO0, bhO1;   // odd-kt set

#define LOADB_E(kt) do { size_t ko = (size_t)(kt) * 32;                        \
        bgE0 = *(const h16x8*)(bgP0 + ko); bgE1 = *(const h16x8*)(bgP1 + ko);  \
        bhE0 = *(const h16x8*)(bhP0 + ko); bhE1 = *(const h16x8*)(bhP1 + ko); } while (0)
#define LOADB_O(kt) do { size_t ko = (size_t)(kt) * 32;                        \
        bgO0 = *(const h16x8*)(bgP0 + ko); bgO1 = *(const h16x8*)(bgP1 + ko);  \
        bhO0 = *(const h16x8*)(bhP0 + ko); bhO1 = *(const h16x8*)(bhP1 + ko); } while (0)

#define MFMA_PHASE(buf, BG0, BG1, BH0, BH1) do {                               \
        const u16* Ab = sm.s.A[buf];                                           \
        h16x8 ah[4];                                                           \
        _Pragma("unroll")                                                      \
        for (int tr = 0; tr < 4; ++tr)                                         \
            ah[tr] = *(const h16x8*)&Ab[aoff[tr]];                             \
        _Pragma("unroll")                                                      \
        for (int tr = 0; tr < 4; ++tr) {                                       \
            accg[tr][0] = __builtin_amdgcn_mfma_f32_16x16x32_f16(ah[tr], BG0, accg[tr][0], 0, 0, 0); \
            acch[tr][0] = __builtin_amdgcn_mfma_f32_16x16x32_f16(ah[tr], BH0, acch[tr][0], 0, 0, 0); \
        }                                                                      \
        _Pragma("unroll")                                                      \
        for (int tr = 0; tr < 4; ++tr) {                                       \
            accg[tr][1] = __builtin_amdgcn_mfma_f32_16x16x32_f16(ah[tr], BG1, accg[tr][1], 0, 0, 0); \
            acch[tr][1] = __builtin_amdgcn_mfma_f32_16x16x32_f16(ah[tr], BH1, acch[tr][1], 0, 0, 0); \
        }                                                                      \
    } while (0)

    // prologue: B regs + A tile for kt=0
    LOADB_E(0);
    STAGE_A(0, 0);
    __syncthreads();          // one full vmcnt(0) stall, once

    for (int t = 0; t < 16; ++t) {
        const int kt = 2 * t;
        // even phase: compute kt from buf0 + E set; prefetch kt+1 (odd set, buf1)
        LOADB_O(kt + 1);                        // issue B FIRST (oldest in queue)
        STAGE_A(1, kt + 1);
        MFMA_PHASE(0, bgE0, bgE1, bhE0, bhE1);
        __syncthreads();                        // vmcnt(0): B-odd + A-buf1 landed

        // odd phase: compute kt+1 from buf1 + O set; prefetch kt+2 (even, buf0)
        if (t < 15) {
            LOADB_E(kt + 2);
            STAGE_A(0, kt + 2);
        }
        MFMA_PHASE(1, bgO0, bgO1, bhO0, bhO1);
        __syncthreads();
    }
#undef STAGE_A
#undef LOADB_E
#undef LOADB_O
#undef MFMA_PHASE

    // ---- epilogue: 4 slabs of 32 rows (= 1 scan chunk each) ----
    float bgv[2], bhv[2];
#pragma unroll
    for (int tc = 0; tc < 2; ++tc) {
        int el = e0 + wc * 32 + tc * 16 + lr;
        bgv[tc] = bg[el];
        bhv[tc] = bh[el];
    }

#pragma unroll
    for (int s = 0; s < 4; ++s) {
        __syncthreads();  // staging / previous slab reads complete
        if (wr == (s >> 1)) {                 // 4 of 8 waves hold this slab
#pragma unroll
            for (int half = 0; half < 2; ++half) {
                int tr = (s & 1) * 2 + half;
#pragma unroll
                for (int tc = 0; tc < 2; ++tc) {
                    int el = wc * 32 + tc * 16 + lr;
#pragma unroll
                    for (int i = 0; i < 4; ++i) {
                        int row = half * 16 + kg * 4 + i;   // 0..31 in slab
                        sm.ep.g[row][el] = fast_sigmoid(accg[tr][tc][i] + bgv[tc]);
                        sm.ep.c[row][el] = fast_tanh(acch[tr][tc][i] + bhv[tc]);
                    }
                }
            }
        }
        __syncthreads();

        // coalesced fp16 stores: one h16x8 per thread per array (512 = 32x16)
        {
            int row = tid >> 4;               // 0..31
            int c8  = (tid & 15) * 8;
            size_t gofs = (size_t)(m0 + s * 32 + row) * E_DIM + e0 + c8;
            f32x4 v0 = *(const f32x4*)&sm.ep.g[row][c8];
            f32x4 v1 = *(const f32x4*)&sm.ep.g[row][c8 + 4];
            h16x8 hv;
#pragma unroll
            for (int j = 0; j < 4; ++j) { hv[j] = (_Float16)v0[j]; hv[j + 4] = (_Float16)v1[j]; }
            *(h16x8*)(g_out + gofs) = hv;
            v0 = *(const f32x4*)&sm.ep.c[row][c8];
            v1 = *(const f32x4*)&sm.ep.c[row][c8 + 4];
#pragma unroll
            for (int j = 0; j < 4; ++j) { hv[j] = (_Float16)v0[j]; hv[j + 4] = (_Float16)v1[j]; }
            *(h16x8*)(c_out + gofs) = hv;
        }

        // per-chunk affine composite from the fp16-ROUNDED values (consistent
        // with what chunk_apply reads back). col = tid, 128 cols.
        if (tid < 128) {
            float A = 1.f, Bv = 0.f;
#pragma unroll 8
            for (int t = 0; t < LCH; ++t) {
                float g = (float)(_Float16)sm.ep.g[t][tid];
                float c = (float)(_Float16)sm.ep.c[t][tid];
                A  = g * A;
                Bv = g * Bv + (1.f - g) * c;
            }
            int m_abs = m0 + s * 32;
            int b  = m_abs >> 12;             // / 4096
            int ch = (m_abs & 4095) >> 5;     // chunk within sequence
            size_t o = ((size_t)b * NCH + ch) * 1024 + e0 + tid;
            Ac[o] = A;
            Bc[o] = Bv;
        }
    }
}

// ---------------- scan pass 2: prefix over chunks -> h at chunk entry ----------------
__global__ void chunk_prefix(const float* __restrict__ Ac, const float* __restrict__ Bc,
                             const float* __restrict__ hidden, float* __restrict__ Hst) {
    int idx = blockIdx.x * 256 + threadIdx.x;   // 0..8191
    int b = idx >> 10;
    int d = idx & 1023;
    float h = hidden[b * 1024 + d];
#pragma unroll 8
    for (int ch = 0; ch < NCH; ++ch) {
        size_t o = ((size_t)b * NCH + ch) * 1024 + d;
        float A = Ac[o], Bv = Bc[o];
        Hst[o] = h;
        h = A * h + Bv;
    }
}

// ---------------- scan pass 3: apply ----------------
// grid (NCH/2, B), 256 threads = 2 chunks per block, 8 ch/thread (16B loads)
__global__ void chunk_apply(const _Float16* __restrict__ g_arr,
                            const _Float16* __restrict__ c_arr,
                            const float* __restrict__ Hst,
                            float* __restrict__ out) {
    int half = threadIdx.x >> 7;                 // chunk within pair
    int d8   = (threadIdx.x & 127) * 8;
    int ch = blockIdx.x * 2 + half;
    int b  = blockIdx.y;
    size_t base = ((size_t)b * 4096 + (size_t)ch * LCH) * 1024 + d8;
    size_t ho = ((size_t)b * NCH + ch) * 1024 + d8;
    f32x4 h0 = *(const f32x4*)(Hst + ho);
    f32x4 h1 = *(const f32x4*)(Hst + ho + 4);
    float h[8] = {h0[0], h0[1], h0[2], h0[3], h1[0], h1[1], h1[2], h1[3]};
#pragma unroll 4
    for (int t = 0; t < LCH; ++t) {
        size_t idx = base + (size_t)t * 1024;
        h16x8 gv = *(const h16x8*)(g_arr + idx);
        h16x8 cv = *(const h16x8*)(c_arr + idx);
#pragma unroll
        for (int j = 0; j < 8; ++j) {
            float g = (float)gv[j];
            float c = (float)cv[j];
            h[j] = g * h[j] + (1.f - g) * c;
        }
        *(f32x4*)(out + idx)     = (f32x4){h[0], h[1], h[2], h[3]};
        *(f32x4*)(out + idx + 4) = (f32x4){h[4], h[5], h[6], h[7]};
    }
}

extern "C" void kernel_launch(void* const* d_in, const int* in_sizes, int n_in,
                              void* d_out, int out_size, void* d_ws, size_t ws_size,
                              hipStream_t stream) {
    const float* x      = (const float*)d_in[0];
    const float* hidden = (const float*)d_in[1];
    const float* Wg     = (const float*)d_in[2];
    const float* bg     = (const float*)d_in[3];
    const float* Wh     = (const float*)d_in[4];
    const float* bh     = (const float*)d_in[5];
    float* out = (float*)d_out;

    char* ws = (char*)d_ws;
    const size_t WSEG = 2u * 1024u * 1024u;            // 2MB per W (fp16)
    u16* wg_h = (u16*)(ws + 0 * WSEG);
    u16* wh_h = (u16*)(ws + 1 * WSEG);                 // segs 2,3 spare
    const size_t HBYTES = (size_t)M_TOTAL * E_DIM * 2; // 64 MiB per fp16 array
    _Float16* g_arr = (_Float16*)(ws + 4 * WSEG);
    _Float16* c_arr = (_Float16*)(ws + 4 * WSEG + HBYTES);
    const size_t SSEG = (size_t)8 * NCH * 1024 * 4;    // 4 MiB per scan array
    float* Ac  = (float*)(ws + 4 * WSEG + 2 * HBYTES);
    float* Bc  = (float*)(ws + 4 * WSEG + 2 * HBYTES + SSEG);
    float* Hst = (float*)(ws + 4 * WSEG + 2 * HBYTES + 2 * SSEG);

    // x16 scratch lives in d_out (64MB of its 128MB); chunk_apply overwrites
    // all of d_out afterwards, so this is safe in stream order.
    u16* x16 = (u16*)d_out;

    // 1) convert x + weights to fp16 (grid-stride, 2048 blocks)
    prep<<<dim3(2048), 256, 0, stream>>>(x, Wg, Wh, x16, wg_h, wh_h);

    // 2) fused dual GEMM + activation + per-chunk composite (XCD-swizzled grid)
    gemm_act<<<dim3(2048), 512, 0, stream>>>(
        x16, wg_h, wh_h, bg, bh, g_arr, c_arr, Ac, Bc);

    // 3) chunked scan (compose fused into gemm_act epilogue)
    chunk_prefix<<<dim3(32), 256, 0, stream>>>(Ac, Bc, hidden, Hst);
    chunk_apply<<<dim3(NCH / 2, 8), 256, 0, stream>>>(g_arr, c_arr, Hst, out);
}

// Round 7
// 457.637 us; speedup vs baseline: 1.2701x; 1.2701x over previous
//
#include <hip/hip_runtime.h>
#include <hip/hip_bf16.h>
#include <cstdint>

// MinGRU: g=sigmoid(xWg^T+bg), c=tanh(xWh^T+bh), h_t = g*h_{t-1} + (1-g)*c
// B=8, L=4096, D=1024.  M = B*L = 32768, K = E = 1024.
//
// R10 (from R9 post-mortem: B-direct thrashed L2 (FETCH 98->145MB) and the
// compiler's vmcnt(0)-before-__syncthreads exposed load latency every step;
// R7's all-LDS staging at 183us/33% MfmaUtil was the documented 2-barrier
// ceiling). R10 = R7 staging + T3/T4 counted-vmcnt schedule:
//  - prologue stages tiles 0,1 (6 loads in flight). Per K-step:
//      s_waitcnt vmcnt(3)   // tile kt landed; tile kt+1 stays in flight
//      s_barrier            // raw: NO drain
//      ds_read frags; setprio(1); 16 MFMA; setprio(0)
//      s_barrier            // all waves done reading buf[cur]
//      STAGE(cur, kt+2)     // overwrite safely, 2 slots to land
//    Final tile: vmcnt(0). Loads never drained to 0 mid-loop.
//  - A+B staged via global_load_lds (3 x 16B per thread per step), double
//    buffer, 16B-chunk XOR swizzle both sides (0 conflicts, verified R7/R8).
//  - 512 threads, 8 waves (2m x 4e), wave tile 64x32/GEMM, 2 blocks/CU.
//  - epilogue: 4x 32-row slabs, fused per-chunk scan composite.
// ws layout: Wg16 2M | Wh16 2M | (2M spare x2) | g fp16 64MiB | c fp16 64MiB
//            | Ac 4M | Bc 4M | Hst 4M   (x16 lives in d_out)

using u16   = unsigned short;
using f32x4 = __attribute__((ext_vector_type(4))) float;
using h16x4 = __attribute__((ext_vector_type(4))) _Float16;
using h16x8 = __attribute__((ext_vector_type(8))) _Float16;

#define M_TOTAL 32768
#define K_DIM   1024
#define E_DIM   1024
#define LCH     32     // scan chunk length
#define NCH     128    // chunks per sequence (4096/32)

// ---------------- prepass: x, Wg, Wh -> fp16 (RTNE), grid-stride ----------------
__global__ void prep(const float* __restrict__ x,
                     const float* __restrict__ wg, const float* __restrict__ wh,
                     u16* __restrict__ x16, u16* __restrict__ wg16,
                     u16* __restrict__ wh16) {
    const size_t XQ = (size_t)M_TOTAL * K_DIM / 4;   // 8388608 quads
    const size_t WQ = (size_t)K_DIM * E_DIM / 4;     // 262144 quads
    const size_t TOT = XQ + 2 * WQ;
    for (size_t i = (size_t)blockIdx.x * 256 + threadIdx.x; i < TOT;
         i += (size_t)2048 * 256) {
        const float* src;
        u16* dst;
        size_t j;
        if (i < XQ)           { src = x;  dst = x16;  j = i; }
        else if (i < XQ + WQ) { src = wg; dst = wg16; j = i - XQ; }
        else                  { src = wh; dst = wh16; j = i - XQ - WQ; }
        f32x4 f = ((const f32x4*)src)[j];
        h16x4 h;
#pragma unroll
        for (int c = 0; c < 4; ++c) h[c] = (_Float16)f[c];
        ((h16x4*)dst)[j] = h;
    }
}

__device__ inline float fast_sigmoid(float z) {
    return 1.f / (1.f + __expf(-z));
}
__device__ inline float fast_tanh(float z) {
    return 1.f - 2.f / (__expf(2.f * z) + 1.f);  // saturates correctly
}

// ---------------- GEMM + activation + per-chunk composite ----------------
// 1D grid of 2048 blocks, XCD-swizzled; 512 threads.
__global__ __launch_bounds__(512, 4) void gemm_act(
    const u16* __restrict__ x16,
    const u16* __restrict__ wg_h, const u16* __restrict__ wh_h,
    const float* __restrict__ bg, const float* __restrict__ bh,
    _Float16* __restrict__ g_out, _Float16* __restrict__ c_out,
    float* __restrict__ Ac, float* __restrict__ Bc) {

    // XCD decode: each XCD owns 32 consecutive m-tiles, e fastest -> the 8
    // blocks sharing an x m-tile are temporally adjacent on one XCD (L2 reuse).
    const int bid   = blockIdx.x;
    const int xcd   = bid & 7;
    const int local = bid >> 3;              // 0..255
    const int mt    = xcd * 32 + (local >> 3);
    const int et    = local & 7;
    const int e0    = et * 128;
    const int m0    = mt * 128;

    // Double-buffered staging; each tile = A 8KB + B 2x8KB = 24KB.
    // Layout: 64 lines x 128B (line = row-pair), chunk slot c holds global
    // chunk c^(line&7) -> conflict-free swizzled ds_reads, linear DMA dest.
    __shared__ __align__(16) union SM {
        struct {
            u16 A[512 * 8];       // 8KB
            u16 B[2][512 * 8];    // 16KB
        } buf[2];
        struct {
            float g[32][132];
            float c[32][132];
        } ep;
    } sm;

    const int tid  = threadIdx.x;
    const int lane = tid & 63;
    const int wave = tid >> 6;                // 0..7
    const int wr = wave >> 2, wc = wave & 3;  // 2x4 wave grid, wave tile 64x32
    const int lr = lane & 15;                 // row/col within 16
    const int kg = lane >> 4;                 // k-group (quad)

    // ---- per-thread staging source decode (kt-invariant part) ----
    // thread stages chunk ch=tid of each region: line p=ch>>3, slot c=ch&7,
    // logical chunk clog = c ^ (p&7): row = 2p + (clog>>2), kc = clog&3.
    const int sp    = tid >> 3;
    const int sc    = tid & 7;
    const int sclog = sc ^ (sp & 7);
    const int srow  = sp * 2 + (sclog >> 2);
    const int skc   = sclog & 3;
    const u16* aSrc  = x16  + (size_t)(m0 + srow) * K_DIM + skc * 8;
    const u16* bgSrc = wg_h + (size_t)(e0 + srow) * K_DIM + skc * 8;
    const u16* bhSrc = wh_h + (size_t)(e0 + srow) * K_DIM + skc * 8;

    // ---- fragment LDS element-offsets (kt-invariant, hoisted) ----
    int aoff[4], boff[2];
#pragma unroll
    for (int tr = 0; tr < 4; ++tr) {
        int r = wr * 64 + tr * 16 + lr;
        int p = r >> 1;
        int c = (((r & 1) << 2) | kg) ^ (p & 7);
        aoff[tr] = p * 64 + c * 8;
    }
#pragma unroll
    for (int tc = 0; tc < 2; ++tc) {
        int e = wc * 32 + tc * 16 + lr;
        int p = e >> 1;
        int c = (((e & 1) << 2) | kg) ^ (p & 7);
        boff[tc] = p * 64 + c * 8;
    }

    f32x4 accg[4][2], acch[4][2];
#pragma unroll
    for (int tr = 0; tr < 4; ++tr)
#pragma unroll
        for (int tc = 0; tc < 2; ++tc) {
            accg[tr][tc] = (f32x4){0.f, 0.f, 0.f, 0.f};
            acch[tr][tc] = (f32x4){0.f, 0.f, 0.f, 0.f};
        }

#define STAGE(bi, kt)                                                          \
    do {                                                                       \
        size_t ko = (size_t)(kt) * 32;                                         \
        __builtin_amdgcn_global_load_lds(                                      \
            (const __attribute__((address_space(1))) void*)(aSrc + ko),        \
            (__attribute__((address_space(3))) void*)(&sm.buf[bi].A[tid * 8]), \
            16, 0, 0);                                                         \
        __builtin_amdgcn_global_load_lds(                                      \
            (const __attribute__((address_space(1))) void*)(bgSrc + ko),       \
            (__attribute__((address_space(3))) void*)(&sm.buf[bi].B[0][tid * 8]),\
            16, 0, 0);                                                         \
        __builtin_amdgcn_global_load_lds(                                      \
            (const __attribute__((address_space(1))) void*)(bhSrc + ko),       \
            (__attribute__((address_space(3))) void*)(&sm.buf[bi].B[1][tid * 8]),\
            16, 0, 0);                                                         \
    } while (0)

#define PHASE(bi)                                                              \
    do {                                                                       \
        const u16* Ab = sm.buf[bi].A;                                          \
        const u16* Bg = sm.buf[bi].B[0];                                       \
        const u16* Bh = sm.buf[bi].B[1];                                       \
        h16x8 ah[4];                                                           \
        _Pragma("unroll")                                                      \
        for (int tr = 0; tr < 4; ++tr)                                         \
            ah[tr] = *(const h16x8*)&Ab[aoff[tr]];                             \
        h16x8 bgv0 = *(const h16x8*)&Bg[boff[0]];                              \
        h16x8 bhv0 = *(const h16x8*)&Bh[boff[0]];                              \
        h16x8 bgv1 = *(const h16x8*)&Bg[boff[1]];                              \
        h16x8 bhv1 = *(const h16x8*)&Bh[boff[1]];                              \
        __builtin_amdgcn_s_setprio(1);                                         \
        _Pragma("unroll")                                                      \
        for (int tr = 0; tr < 4; ++tr) {                                       \
            accg[tr][0] = __builtin_amdgcn_mfma_f32_16x16x32_f16(ah[tr], bgv0, accg[tr][0], 0, 0, 0); \
            acch[tr][0] = __builtin_amdgcn_mfma_f32_16x16x32_f16(ah[tr], bhv0, acch[tr][0], 0, 0, 0); \
        }                                                                      \
        _Pragma("unroll")                                                      \
        for (int tr = 0; tr < 4; ++tr) {                                       \
            accg[tr][1] = __builtin_amdgcn_mfma_f32_16x16x32_f16(ah[tr], bgv1, accg[tr][1], 0, 0, 0); \
            acch[tr][1] = __builtin_amdgcn_mfma_f32_16x16x32_f16(ah[tr], bhv1, acch[tr][1], 0, 0, 0); \
        }                                                                      \
        __builtin_amdgcn_s_setprio(0);                                         \
    } while (0)

    // prologue: tiles 0 and 1 in flight (6 loads/wave)
    STAGE(0, 0);
    STAGE(1, 1);

    int cur = 0;
    for (int kt = 0; kt < 31; ++kt) {
        // tile kt's 3 loads are the oldest; allow tile kt+1's 3 to remain.
        asm volatile("s_waitcnt vmcnt(3)" ::: "memory");
        __builtin_amdgcn_s_barrier();          // raw: no drain
        PHASE(cur);
        __builtin_amdgcn_s_barrier();          // all waves done with buf[cur]
        if (kt < 30) STAGE(cur, kt + 2);       // overwrite; 2 slots to land
        cur ^= 1;
    }
    // final tile (kt=31): nothing else in flight
    asm volatile("s_waitcnt vmcnt(0)" ::: "memory");
    __builtin_amdgcn_s_barrier();
    PHASE(cur);
#undef STAGE
#undef PHASE

    // ---- epilogue: 4 slabs of 32 rows (= 1 scan chunk each) ----
    float bgv[2], bhv[2];
#pragma unroll
    for (int tc = 0; tc < 2; ++tc) {
        int el = e0 + wc * 32 + tc * 16 + lr;
        bgv[tc] = bg[el];
        bhv[tc] = bh[el];
    }

#pragma unroll
    for (int s = 0; s < 4; ++s) {
        __syncthreads();  // staging / previous slab reads complete
        if (wr == (s >> 1)) {                 // 4 of 8 waves hold this slab
#pragma unroll
            for (int half = 0; half < 2; ++half) {
                int tr = (s & 1) * 2 + half;
#pragma unroll
                for (int tc = 0; tc < 2; ++tc) {
                    int el = wc * 32 + tc * 16 + lr;
#pragma unroll
                    for (int i = 0; i < 4; ++i) {
                        int row = half * 16 + kg * 4 + i;   // 0..31 in slab
                        sm.ep.g[row][el] = fast_sigmoid(accg[tr][tc][i] + bgv[tc]);
                        sm.ep.c[row][el] = fast_tanh(acch[tr][tc][i] + bhv[tc]);
                    }
                }
            }
        }
        __syncthreads();

        // coalesced fp16 stores: one h16x8 per thread per array (512 = 32x16)
        {
            int row = tid >> 4;               // 0..31
            int c8  = (tid & 15) * 8;
            size_t gofs = (size_t)(m0 + s * 32 + row) * E_DIM + e0 + c8;
            f32x4 v0 = *(const f32x4*)&sm.ep.g[row][c8];
            f32x4 v1 = *(const f32x4*)&sm.ep.g[row][c8 + 4];
            h16x8 hv;
#pragma unroll
            for (int j = 0; j < 4; ++j) { hv[j] = (_Float16)v0[j]; hv[j + 4] = (_Float16)v1[j]; }
            *(h16x8*)(g_out + gofs) = hv;
            v0 = *(const f32x4*)&sm.ep.c[row][c8];
            v1 = *(const f32x4*)&sm.ep.c[row][c8 + 4];
#pragma unroll
            for (int j = 0; j < 4; ++j) { hv[j] = (_Float16)v0[j]; hv[j + 4] = (_Float16)v1[j]; }
            *(h16x8*)(c_out + gofs) = hv;
        }

        // per-chunk affine composite from the fp16-ROUNDED values (consistent
        // with what chunk_apply reads back). col = tid, 128 cols.
        if (tid < 128) {
            float A = 1.f, Bv = 0.f;
#pragma unroll 8
            for (int t = 0; t < LCH; ++t) {
                float g = (float)(_Float16)sm.ep.g[t][tid];
                float c = (float)(_Float16)sm.ep.c[t][tid];
                A  = g * A;
                Bv = g * Bv + (1.f - g) * c;
            }
            int m_abs = m0 + s * 32;
            int b  = m_abs >> 12;             // / 4096
            int ch = (m_abs & 4095) >> 5;     // chunk within sequence
            size_t o = ((size_t)b * NCH + ch) * 1024 + e0 + tid;
            Ac[o] = A;
            Bc[o] = Bv;
        }
    }
}

// ---------------- scan pass 2: prefix over chunks -> h at chunk entry ----------------
__global__ void chunk_prefix(const float* __restrict__ Ac, const float* __restrict__ Bc,
                             const float* __restrict__ hidden, float* __restrict__ Hst) {
    int idx = blockIdx.x * 256 + threadIdx.x;   // 0..8191
    int b = idx >> 10;
    int d = idx & 1023;
    float h = hidden[b * 1024 + d];
#pragma unroll 8
    for (int ch = 0; ch < NCH; ++ch) {
        size_t o = ((size_t)b * NCH + ch) * 1024 + d;
        float A = Ac[o], Bv = Bc[o];
        Hst[o] = h;
        h = A * h + Bv;
    }
}

// ---------------- scan pass 3: apply ----------------
// grid (NCH/2, B), 256 threads = 2 chunks per block, 8 ch/thread (16B loads)
__global__ void chunk_apply(const _Float16* __restrict__ g_arr,
                            const _Float16* __restrict__ c_arr,
                            const float* __restrict__ Hst,
                            float* __restrict__ out) {
    int half = threadIdx.x >> 7;                 // chunk within pair
    int d8   = (threadIdx.x & 127) * 8;
    int ch = blockIdx.x * 2 + half;
    int b  = blockIdx.y;
    size_t base = ((size_t)b * 4096 + (size_t)ch * LCH) * 1024 + d8;
    size_t ho = ((size_t)b * NCH + ch) * 1024 + d8;
    f32x4 h0 = *(const f32x4*)(Hst + ho);
    f32x4 h1 = *(const f32x4*)(Hst + ho + 4);
    float h[8] = {h0[0], h0[1], h0[2], h0[3], h1[0], h1[1], h1[2], h1[3]};
#pragma unroll 4
    for (int t = 0; t < LCH; ++t) {
        size_t idx = base + (size_t)t * 1024;
        h16x8 gv = *(const h16x8*)(g_arr + idx);
        h16x8 cv = *(const h16x8*)(c_arr + idx);
#pragma unroll
        for (int j = 0; j < 8; ++j) {
            float g = (float)gv[j];
            float c = (float)cv[j];
            h[j] = g * h[j] + (1.f - g) * c;
        }
        *(f32x4*)(out + idx)     = (f32x4){h[0], h[1], h[2], h[3]};
        *(f32x4*)(out + idx + 4) = (f32x4){h[4], h[5], h[6], h[7]};
    }
}

extern "C" void kernel_launch(void* const* d_in, const int* in_sizes, int n_in,
                              void* d_out, int out_size, void* d_ws, size_t ws_size,
                              hipStream_t stream) {
    const float* x      = (const float*)d_in[0];
    const float* hidden = (const float*)d_in[1];
    const float* Wg     = (const float*)d_in[2];
    const float* bg     = (const float*)d_in[3];
    const float* Wh     = (const float*)d_in[4];
    const float* bh     = (const float*)d_in[5];
    float* out = (float*)d_out;

    char* ws = (char*)d_ws;
    const size_t WSEG = 2u * 1024u * 1024u;            // 2MB per W (fp16)
    u16* wg_h = (u16*)(ws + 0 * WSEG);
    u16* wh_h = (u16*)(ws + 1 * WSEG);                 // segs 2,3 spare
    const size_t HBYTES = (size_t)M_TOTAL * E_DIM * 2; // 64 MiB per fp16 array
    _Float16* g_arr = (_Float16*)(ws + 4 * WSEG);
    _Float16* c_arr = (_Float16*)(ws + 4 * WSEG + HBYTES);
    const size_t SSEG = (size_t)8 * NCH * 1024 * 4;    // 4 MiB per scan array
    float* Ac  = (float*)(ws + 4 * WSEG + 2 * HBYTES);
    float* Bc  = (float*)(ws + 4 * WSEG + 2 * HBYTES + SSEG);
    float* Hst = (float*)(ws + 4 * WSEG + 2 * HBYTES + 2 * SSEG);

    // x16 scratch lives in d_out (64MB of its 128MB); chunk_apply overwrites
    // all of d_out afterwards, so this is safe in stream order.
    u16* x16 = (u16*)d_out;

    // 1) convert x + weights to fp16 (grid-stride, 2048 blocks)
    prep<<<dim3(2048), 256, 0, stream>>>(x, Wg, Wh, x16, wg_h, wh_h);

    // 2) fused dual GEMM + activation + per-chunk composite (XCD-swizzled grid)
    gemm_act<<<dim3(2048), 512, 0, stream>>>(
        x16, wg_h, wh_h, bg, bh, g_arr, c_arr, Ac, Bc);

    // 3) chunked scan (compose fused into gemm_act epilogue)
    chunk_prefix<<<dim3(32), 256, 0, stream>>>(Ac, Bc, hidden, Hst);
    chunk_apply<<<dim3(NCH / 2, 8), 256, 0, stream>>>(g_arr, c_arr, Hst, out);
}